// Round 13
// baseline (14.182 us; speedup 1.0000x reference)
//
#include <hip/hip_runtime.h>
#include <math.h>

namespace {

constexpr int NX  = 512;    // data points
constexpr int M   = 514;    // basis functions
constexpr int NE  = 8192;   // eval points
constexpr int NBC = 256;    // batch*channels
constexpr int PPB = 16;     // eval points per block
constexpr int NBLK = NE / PPB;      // 512 blocks
constexpr int CHUNKS = 8;           // float4 chunks staged per bc row (exactly)
constexpr int SLOTS  = CHUNKS * 4;  // 32 staged columns (need <= 25+3 align)
constexpr int STRIDE = 33;          // odd -> conflict-free LDS rows
constexpr int TAPS = 21;            // H row support: j = i-10+t, t=0..20

// ---------------------------------------------------------------------------
// Compile-time H = (BtB + S I)^-1 Bt, truncated to 21 taps per row (decay
// ~0.268^d; truncation err ~5e-7 rel). Edge rows via local solves (forward
// pass of e_i is exactly 0 below row i; backward warm-up 0.268^16); interior
// rows share one Toeplitz stencil.
// ---------------------------------------------------------------------------
constexpr double dknot(int j) {
    int c = j - 3;
    c = c < 0 ? 0 : (c > NX - 1 ? NX - 1 : c);
    return -1.0 + 2.0 * (double)c / 511.0;
}

constexpr double csqrt(double x) {
    double r = x > 1.0 ? x : 1.0;
    for (int k = 0; k < 50; ++k) r = 0.5 * (r + x / r);
    return r;
}

struct HTab { alignas(16) float h[M][24]; };   // [i][t], t=21..23 pad

constexpr HTab make_h() {
    HTab T{};
    // basis at data points (double de Boor)
    double bx[NX][4] = {};
    for (int n = 0; n < NX; ++n) {
        const int off = n < NX - 1 ? n : NX - 2;
        const double x = -1.0 + 2.0 * (double)n / 511.0;
        double N[4] = {1.0, 0.0, 0.0, 0.0};
        for (int dd = 1; dd <= 3; ++dd) {
            double saved = 0.0;
            for (int r = 0; r < dd; ++r) {
                const double tr = dknot(off + 3 + r + 1);
                const double tl = dknot(off + 3 + r + 1 - dd);
                const double temp = N[r] / (tr - tl);
                N[r] = saved + (tr - x) * temp;
                saved = (x - tl) * temp;
            }
            N[dd] = saved;
        }
        for (int r = 0; r < 4; ++r) bx[n][r] = N[r];
    }
    // banded BtB + S
    double A0[M] = {}, A1[M] = {}, A2[M] = {}, A3[M] = {};
    for (int i = 0; i < M; ++i) {
        double a0 = 1e-3, a1 = 0.0, a2 = 0.0, a3 = 0.0;
        const int nlo = i - 3 < 0 ? 0 : i - 3;
        const int nhi = i + 1 > NX - 1 ? NX - 1 : i + 1;
        for (int n = nlo; n <= nhi; ++n) {
            const int off = n < NX - 1 ? n : NX - 2;
            const int ri = i - off;
            if (ri < 0 || ri > 3) continue;
            const double bi = bx[n][ri];
            a0 += bi * bx[n][ri];
            if (ri >= 1) a1 += bi * bx[n][ri - 1];
            if (ri >= 2) a2 += bi * bx[n][ri - 2];
            if (ri >= 3) a3 += bi * bx[n][ri - 3];
        }
        A0[i] = a0; A1[i] = a1; A2[i] = a2; A3[i] = a3;
    }
    // banded Cholesky (ld = 1/diag), padded +3 with zeros
    double ld[M + 3] = {}, l1a[M + 3] = {}, l2a[M + 3] = {}, l3a[M + 3] = {};
    {
        double rd1 = 0.0, l1p = 0.0, l2p = 0.0, rd2 = 0.0, l1pp = 0.0, rd3 = 0.0;
        for (int i = 0; i < M; ++i) {
            const double l3 = A3[i] * rd3;
            const double l2 = (A2[i] - l3 * l1pp) * rd2;
            const double l1 = (A1[i] - l3 * l2p - l2 * l1p) * rd1;
            const double s  = A0[i] - l3 * l3 - l2 * l2 - l1 * l1;
            const double rd = 1.0 / csqrt(s);
            ld[i] = rd; l1a[i] = l1; l2a[i] = l2; l3a[i] = l3;
            rd3 = rd2; rd2 = rd1; rd1 = rd;
            l1pp = l1p; l1p = l1; l2p = l2;
        }
    }
    constexpr int ILO = 40, IHI = 473, IREF = 250;
    // per-row Green's column (local solve) + H assembly
    for (int i = 0; i < M; ++i) {
        const bool interior = (i >= ILO && i <= IHI);
        if (interior && i != IREF) continue;
        double y[44] = {};   // fwd solution, rows i-14+k; exactly 0 below i
        for (int k = 14; k < 44; ++k) {
            const int row = i - 14 + k;
            if (row >= M) break;
            const double b = (row == i) ? 1.0 : 0.0;
            const double ym1 = y[k - 1], ym2 = y[k - 2], ym3 = y[k - 3];
            y[k] = (b - l1a[row] * ym1 - l2a[row] * ym2 - l3a[row] * ym3) * ld[row];
        }
        double g[44] = {};   // G[i][i-14+k]
        for (int k = 43; k >= 0; --k) {
            const int row = i - 14 + k;
            if (row > M - 1) continue;
            if (row < 0) break;
            const double cp1 = k + 1 < 44 ? g[k + 1] : 0.0;
            const double cp2 = k + 2 < 44 ? g[k + 2] : 0.0;
            const double cp3 = k + 3 < 44 ? g[k + 3] : 0.0;
            g[k] = (y[k] - l1a[row + 1] * cp1 - l2a[row + 2] * cp2 - l3a[row + 3] * cp3) * ld[row];
        }
        for (int t = 0; t < TAPS; ++t) {
            const int j = i - 10 + t;
            double s = 0.0;
            if (j >= 0 && j <= NX - 1) {
                const int off = j < NX - 1 ? j : NX - 2;
                for (int r = 0; r < 4; ++r) {
                    const int idx = off + r;              // in [j, j+3]
                    const int k = idx - (i - 14);         // in [4, 27]
                    const double gv = (idx <= M - 1) ? g[k] : 0.0;
                    s += bx[j][r] * gv;
                }
            }
            T.h[i][t] = (float)s;
        }
        for (int t = TAPS; t < 24; ++t) T.h[i][t] = 0.0f;
    }
    for (int i = ILO; i <= IHI; ++i) {
        if (i == IREF) continue;
        for (int t = 0; t < 24; ++t) T.h[i][t] = T.h[IREF][t];
    }
    return T;
}

__constant__ HTab HC = make_h();

// interval index of eval point n (single fp32 path everywhere)
__device__ __forceinline__ int offf(int n) {
    const float xe = -1.0f + 2.0f * (float)n / 8191.0f;
    int off = (int)((xe + 1.0f) * 255.5f);
    return off < 0 ? 0 : (off > NX - 2 ? NX - 2 : off);
}

__device__ __forceinline__ float knotf(int j) {
    int c = j - 3;
    c = c < 0 ? 0 : (c > NX - 1 ? NX - 1 : c);
    return -1.0f + 2.0f * (float)c / 511.0f;
}

__device__ __forceinline__ void deboor3(float x, int j, float N[4]) {
    N[0] = 1.0f; N[1] = 0.0f; N[2] = 0.0f; N[3] = 0.0f;
#pragma unroll
    for (int d = 1; d <= 3; ++d) {
        float saved = 0.0f;
#pragma unroll
        for (int r = 0; r < 3; ++r) {
            if (r < d) {
                const float tr = knotf(j + r + 1);
                const float tl = knotf(j + r + 1 - d);
                const float temp = N[r] / (tr - tl);
                N[r] = saved + (tr - x) * temp;
                saved = (x - tl) * temp;
            }
        }
        N[d] = saved;
    }
}

// ---------------------------------------------------------------------------
// Single fused kernel, chain-free. Block b: eval points [b*16, b*16+16) x all
// 256 bc. Stage Z window (exactly 8 float4/thread) into LDS; 16 threads
// compute shared de Boor weights meanwhile; barrier; each thread (= one bc)
// reads its 25-col z row, forms 5 coef values as 21-tap dots with the
// __constant__ H stencil (wave-uniform rows -> scalar loads), evaluates its
// 16 points, writes 4 float4.
// ---------------------------------------------------------------------------
__global__ __launch_bounds__(256) void spline_fused(const float* __restrict__ Z,
                                                    float* __restrict__ out) {
    __shared__ float Bs[NBC * STRIDE + 8];
    __shared__ float NvS[PPB][8];     // Nv[4], so_rel
    const int tid = threadIdx.x;
    const int ns = blockIdx.x * PPB;

    // wave-uniform geometry
    const int e_lo = offf(ns);                 // first coef row needed
    const int n0 = e_lo - 10;                  // first needed Z column
    const int n0a = n0 & ~3;                   // aligned staging base
    const int d = n0 - n0a;                    // slot shift 0..3

    // ---- stage: 8 float4 loads/thread, fully coalesced ----
    {
        const int wid = tid >> 6, lane = tid & 63;
        const int rsub = lane >> 3;    // row within 8-row group
        const int ch = lane & 7;       // float4 chunk 0..7
        int cb = n0a + (ch << 2);
        cb = cb < 0 ? 0 : (cb > NX - 4 ? NX - 4 : cb);  // OOR slots have H=0

        float4 v[8];
#pragma unroll
        for (int it = 0; it < 8; ++it) {
            const int row = (wid << 6) + (it << 3) + rsub;
            v[it] = *(const float4*)(Z + (size_t)row * NX + cb);
        }

        // shared de Boor weights while loads are in flight
        if (tid < PPB) {
            const int n = ns + tid;
            const float xe = -1.0f + 2.0f * (float)n / 8191.0f;
            int off = (int)((xe + 1.0f) * 255.5f);
            off = off < 0 ? 0 : (off > NX - 2 ? NX - 2 : off);
            float N[4];
            deboor3(xe, off + 3, N);
            NvS[tid][0] = N[0]; NvS[tid][1] = N[1];
            NvS[tid][2] = N[2]; NvS[tid][3] = N[3];
            int sr = off - e_lo;
            sr = sr < 0 ? 0 : (sr > 1 ? 1 : sr);
            NvS[tid][4] = (float)sr;
        }

#pragma unroll
        for (int it = 0; it < 8; ++it) {
            const int row = (wid << 6) + (it << 3) + rsub;
            float* wp = Bs + row * STRIDE + (ch << 2);   // scalar writes, odd stride
            wp[0] = v[it].x; wp[1] = v[it].y; wp[2] = v[it].z; wp[3] = v[it].w;
        }
    }
    __syncthreads();

    // ---- per-thread (= bc): z row -> 5 coef dots -> 16 eval points ----
    const float* Brow = Bs + tid * STRIDE + d;   // Brow[s] = Z col n0+s
    float z[25];
#pragma unroll
    for (int s = 0; s < 25; ++s) z[s] = Brow[s];

    float cf[5];
#pragma unroll
    for (int c = 0; c < 5; ++c) {
        int row = e_lo + c;
        row = row < M ? row : M - 1;             // clamp (cf[4] unused when OOR)
        const float* Hr = HC.h[row];             // wave-uniform -> scalar loads
        float acc = 0.0f;
#pragma unroll
        for (int t = 0; t < TAPS; ++t) acc += Hr[t] * z[c + t];
        cf[c] = acc;
    }

    float4 r[4];
#pragma unroll
    for (int p = 0; p < PPB; ++p) {
        const float w0 = NvS[p][0], w1 = NvS[p][1], w2 = NvS[p][2], w3 = NvS[p][3];
        const int sr = (int)NvS[p][4];           // wave-uniform branch
        float v;
        if (sr == 0) v = w0 * cf[0] + w1 * cf[1] + w2 * cf[2] + w3 * cf[3];
        else         v = w0 * cf[1] + w1 * cf[2] + w2 * cf[3] + w3 * cf[4];
        ((float*)&r[p >> 2])[p & 3] = v;
    }
    float* op = out + (size_t)tid * NE + ns;
    *(float4*)(op)      = r[0];
    *(float4*)(op + 4)  = r[1];
    *(float4*)(op + 8)  = r[2];
    *(float4*)(op + 12) = r[3];
}

}  // namespace

extern "C" void kernel_launch(void* const* d_in, const int* in_sizes, int n_in,
                              void* d_out, int out_size, void* d_ws, size_t ws_size,
                              hipStream_t stream) {
    const float* Z = (const float*)d_in[0];
    float* out = (float*)d_out;
    (void)d_ws; (void)ws_size;

    hipLaunchKernelGGL(spline_fused, dim3(NBLK), dim3(256), 0, stream, Z, out);
}